// Round 1
// 575.031 us; speedup vs baseline: 1.0412x; 1.0412x over previous
//
#include <hip/hip_runtime.h>
#include <hip/hip_bf16.h>

// ---------------------------------------------------------------------------
// Types / helpers
// ---------------------------------------------------------------------------
typedef __bf16 bf16x8 __attribute__((ext_vector_type(8)));
typedef float f32x16 __attribute__((ext_vector_type(16)));

// fp32 -> bf16 bits, round-to-nearest-even (inputs are finite; no NaN path)
__device__ __forceinline__ unsigned short f2bs(float f) {
    unsigned u = __builtin_bit_cast(unsigned, f);
    u = (u + 0x7fffu + ((u >> 16) & 1u)) >> 16;
    return (unsigned short)u;
}
__device__ __forceinline__ float bs2f(unsigned short s) {
    unsigned u = ((unsigned)s) << 16;
    return __builtin_bit_cast(float, u);
}

#define GLDS16(gp, lp)                                                        \
    __builtin_amdgcn_global_load_lds(                                         \
        (const __attribute__((address_space(1))) void*)(gp),                  \
        (__attribute__((address_space(3))) void*)(lp), 16, 0, 0)

#define TCHUNK 32

// ---------------------------------------------------------------------------
// Kernel 1a: per-chunk sums + write the h-half of X in bf16.
// ---------------------------------------------------------------------------
__global__ __launch_bounds__(256) void feats_partial(
    const float* __restrict__ h, float* __restrict__ partial,
    unsigned short* __restrict__ X, int B, int T, int D, int nC) {
    const int d = blockIdx.z * 256 + threadIdx.x;
    const int b = blockIdx.x, c = blockIdx.y;
    const int t0 = c * TCHUNK;
    const int t1 = min(t0 + TCHUNK, T);
    const float* hp = h + ((long)b * T + t0) * D + d;
    unsigned short* xp = X + ((long)b * T + t0) * (2 * D) + D + d;
    float s = 0.f;
    for (int t = t0; t < t1; ++t) {
        float v = *hp;
        *xp = f2bs(v);
        s += v;
        hp += D;
        xp += 2 * D;
    }
    partial[((long)b * nC + c) * D + d] = s;
}

// ---------------------------------------------------------------------------
// Kernel 1b: write the prefix-mean half (reads bf16 h-half back).
// ---------------------------------------------------------------------------
__global__ __launch_bounds__(256) void feats_write(
    const float* __restrict__ partial, unsigned short* __restrict__ X,
    int B, int T, int D, int nC) {
    const int d = blockIdx.z * 256 + threadIdx.x;
    const int b = blockIdx.x, c = blockIdx.y;
    const int t0 = c * TCHUNK;
    const int t1 = min(t0 + TCHUNK, T);
    float sum = 0.f;
    for (int cc = 0; cc < c; ++cc)
        sum += partial[((long)b * nC + cc) * D + d];
    unsigned short* xp = X + ((long)b * T + t0) * (2 * D) + d;
    for (int t = t0; t < t1; ++t) {
        float pm = (t == 0) ? 0.f : sum / (float)t;
        xp[0] = f2bs(pm);
        sum += bs2f(xp[D]);
        xp += 2 * D;
    }
}

// ---------------------------------------------------------------------------
// Kernel 2: transpose + cast. W: [K][N] fp32 -> WT: [N][K] bf16 bits.
// ---------------------------------------------------------------------------
__global__ __launch_bounds__(256) void transpose_cast(
    const float* __restrict__ W, unsigned short* __restrict__ WT,
    int K, int N) {
    __shared__ float tile[32][33];
    const int n0 = blockIdx.x * 32, k0 = blockIdx.y * 32;
    const int tx = threadIdx.x, ty = threadIdx.y;
    #pragma unroll
    for (int i = ty; i < 32; i += 8)
        tile[i][tx] = W[(long)(k0 + i) * N + n0 + tx];
    __syncthreads();
    #pragma unroll
    for (int i = ty; i < 32; i += 8)
        WT[(long)(n0 + i) * K + k0 + tx] = f2bs(tile[tx][i]);
}

// ---------------------------------------------------------------------------
// Kernel 2b: out[m] = b3 (init for the fused-head atomics)
// ---------------------------------------------------------------------------
__global__ __launch_bounds__(256) void init_out(
    float* __restrict__ out, const float* __restrict__ b3, int M) {
    int m = blockIdx.x * 256 + threadIdx.x;
    if (m < M) out[m] = b3[0];
}

// ---------------------------------------------------------------------------
// Kernel 3: GEMM  C[M,N] = relu(A[M,K] * BT[N,K]^T + bias)
//
// R10: 256x256 tile, BK=64, 512 threads (8 waves, 2M x 4N), 8-phase
// double-buffered schedule with counted vmcnt (T2+T3+T4+T5 per m201/m218b).
//
// LDS layout: lds[dbuf][A|B][kh][256 rows][32 elems] (K-half planes).
//   - each (dbuf,ab,kh) unit = 16 KiB contiguous -> linear-dest
//     global_load_lds in 2x 512-thread b128 loads.
//   - bank swizzle: 16B chunk c of row r stored at slot c^((r>>1)&3);
//     inverse applied to per-lane GLOBAL source col (both-sides, rule 21).
//     Spreads 8 consecutive rows over all 8 b128 bank-quads.
// Phase p (p=0..3 per K-tile) computes ksub p (one k-slice of 16):
//   phase p reads only plane (p>>1) -> Kh0 is dead after phase 1, Kh1 after
//   phase 3. Stage issue schedule per group t (c=t&1, o=1-c):
//     p0: A-Kh1(t+1)->buf o   p1: B-Kh1(t+1)->buf o
//     p2: A-Kh0(t+2)->buf c   p3: B-Kh0(t+2)->buf c
//   Each unit issues 6 phases before its first read. Single per-group
//   gate: s_waitcnt vmcnt(6) (3 units x 2 loads stay in flight ACROSS
//   barriers; vmcnt(0) only for the final K-tile). Staging-after-read is
//   safe: phase p's ds_reads drain (auto lgkmcnt before MFMA) before the
//   post-MFMA sched_barrier(0)+s_barrier that precedes the overwrite issue.
// REGISTER MODEL: acc 4x2 f32x16 = 128 acc regs + ~60 arch -> 2 waves/EU.
// Never exceed 128 acc regs at 512 threads (R8 lesson).
// LESSONS kept: no min-waves launch_bounds (R4); fused head epilogue;
// C/D layout col=lane&31, row=(reg&3)+8*(reg>>2)+4*(lane>>5) (m74/m101).
// ---------------------------------------------------------------------------

#define PH_READS(c, ks, AF, BF)                                               \
    _Pragma("unroll")                                                         \
    for (int m_ = 0; m_ < 4; ++m_)                                            \
        AF[m_] = *(const bf16x8*)(&lds[c][0][(ks) >> 1][0] +                  \
                                  (baseA[m_] ^ (16 * ((ks) & 1))));           \
    _Pragma("unroll")                                                         \
    for (int n_ = 0; n_ < 2; ++n_)                                            \
        BF[n_] = *(const bf16x8*)(&lds[c][1][(ks) >> 1][0] +                  \
                                  (baseB[n_] ^ (16 * ((ks) & 1))));

#define PH_MFMA(AF, BF)                                                       \
    __builtin_amdgcn_s_setprio(1);                                            \
    _Pragma("unroll")                                                         \
    for (int m_ = 0; m_ < 4; ++m_)                                            \
        _Pragma("unroll")                                                     \
        for (int n_ = 0; n_ < 2; ++n_)                                        \
            acc[m_][n_] = __builtin_amdgcn_mfma_f32_32x32x16_bf16(            \
                AF[m_], BF[n_], acc[m_][n_], 0, 0, 0);                        \
    __builtin_amdgcn_s_setprio(0);

#define GROUP(c, o, t)                                                        \
  {                                                                           \
    /* ---- phase 0 (ksub 0) ---- */                                          \
    if ((t) + 1 < NT) stageA(o, 1, (t) + 1);                                  \
    if ((t) == NT - 1)                                                        \
        asm volatile("s_waitcnt vmcnt(0)" ::: "memory");                      \
    else                                                                      \
        asm volatile("s_waitcnt vmcnt(6)" ::: "memory");                      \
    __builtin_amdgcn_s_barrier();                                             \
    __builtin_amdgcn_sched_barrier(0);                                        \
    {                                                                         \
        bf16x8 af[4], bfr[2];                                                 \
        PH_READS(c, 0, af, bfr);                                              \
        PH_MFMA(af, bfr);                                                     \
    }                                                                         \
    __builtin_amdgcn_sched_barrier(0);                                        \
    __builtin_amdgcn_s_barrier();                                             \
    /* ---- phase 1 (ksub 1) ---- */                                          \
    {                                                                         \
        bf16x8 af[4], bfr[2];                                                 \
        PH_READS(c, 1, af, bfr);                                              \
        if ((t) + 1 < NT) stageB(o, 1, (t) + 1);                              \
        __builtin_amdgcn_s_barrier();                                         \
        PH_MFMA(af, bfr);                                                     \
    }                                                                         \
    __builtin_amdgcn_sched_barrier(0);                                        \
    __builtin_amdgcn_s_barrier();                                             \
    /* ---- phase 2 (ksub 2) ---- */                                          \
    {                                                                         \
        bf16x8 af[4], bfr[2];                                                 \
        PH_READS(c, 2, af, bfr);                                              \
        if ((t) + 2 < NT) stageA(c, 0, (t) + 2);                              \
        __builtin_amdgcn_s_barrier();                                         \
        PH_MFMA(af, bfr);                                                     \
    }                                                                         \
    __builtin_amdgcn_sched_barrier(0);                                        \
    __builtin_amdgcn_s_barrier();                                             \
    /* ---- phase 3 (ksub 3) ---- */                                          \
    {                                                                         \
        bf16x8 af[4], bfr[2];                                                 \
        PH_READS(c, 3, af, bfr);                                              \
        if ((t) + 2 < NT) stageB(c, 0, (t) + 2);                              \
        __builtin_amdgcn_s_barrier();                                         \
        PH_MFMA(af, bfr);                                                     \
    }                                                                         \
    __builtin_amdgcn_sched_barrier(0);                                        \
    __builtin_amdgcn_s_barrier();                                             \
  }

template <bool FUSE>
__global__ __launch_bounds__(512) void gemm_bt_bias_relu(
    const unsigned short* __restrict__ A,   // [M,K] bf16 bits
    const unsigned short* __restrict__ BT,  // [N,K] bf16 bits
    const float* __restrict__ bias,         // [N]
    unsigned short* __restrict__ C,         // [M,N] bf16 bits (unused if FUSE)
    const float* __restrict__ W3,           // [N] head weights (FUSE only)
    float* __restrict__ outp,               // [M] (FUSE only)
    int M, int N, int K) {
    // [dbuf][A=0/B=1][kh][row*32 + slot*8 .. ] : 128 KiB total
    __shared__ __align__(16) unsigned short lds[2][2][2][8192];

    const int tid = threadIdx.x;
    const int lane = tid & 63;
    const int wave = tid >> 6;
    const int wm = wave >> 2;   // 0..1 -> rows wm*128..+127
    const int wn = wave & 3;    // 0..3 -> cols wn*64..+63
    const int l31 = lane & 31;
    const int half = lane >> 5;

    // ---- bijective XCD-chunked swizzle (m204), column-major tile order ----
    const int nRow = M >> 8;
    const int nCol = N >> 8;
    const int nwg = nRow * nCol;
    const int q = nwg >> 3, r = nwg & 7;
    const int x = blockIdx.x & 7;
    const int sidx = blockIdx.x >> 3;
    const int wg = (x < r ? x * (q + 1) : r * (q + 1) + (x - r) * q) + sidx;
    const int col_blk = wg / nRow;
    const int row_blk = wg - col_blk * nRow;
    const long row0 = (long)row_blk * 256;
    const long col0 = (long)col_blk * 256;

    // ---- staging source (pre-swizzled global col, rule 21) ----
    // thread covers one 16B chunk: row = tid>>2 (+i*128), slot = tid&3,
    // global chunk = slot ^ ((row>>1)&3) = (tid&3) ^ ((tid>>3)&3)
    const int sg = ((tid & 3) ^ ((tid >> 3) & 3)) * 8;
    const unsigned short* Ab = A + (row0 + (tid >> 2)) * K + sg;
    const unsigned short* Bb = BT + (col0 + (tid >> 2)) * K + sg;

    auto stageA = [&](int c, int kh, int kt) {
        GLDS16(Ab + (long)kt * 64 + kh * 32, &lds[c][0][kh][tid * 8]);
        GLDS16(Ab + (long)128 * K + (long)kt * 64 + kh * 32,
               &lds[c][0][kh][(512 + tid) * 8]);
    };
    auto stageB = [&](int c, int kh, int kt) {
        GLDS16(Bb + (long)kt * 64 + kh * 32, &lds[c][1][kh][tid * 8]);
        GLDS16(Bb + (long)128 * K + (long)kt * 64 + kh * 32,
               &lds[c][1][kh][(512 + tid) * 8]);
    };

    // ---- per-lane LDS read offsets (elements within a plane) ----
    // frag (m, ksub): row = wm*128+m*32+l31, k = ksub*16 + half*8
    // plane = ksub>>1, chunk = half ^ 2*(ksub&1), slot = chunk^((row>>1)&3)
    int baseA[4], baseB[2];
    #pragma unroll
    for (int m = 0; m < 4; ++m) {
        int ra = wm * 128 + m * 32 + l31;
        baseA[m] = ra * 32 + ((half ^ ((ra >> 1) & 3)) * 8);
    }
    #pragma unroll
    for (int n = 0; n < 2; ++n) {
        int rb = wn * 64 + n * 32 + l31;
        baseB[n] = rb * 32 + ((half ^ ((rb >> 1) & 3)) * 8);
    }

    f32x16 acc[4][2];
    #pragma unroll
    for (int i = 0; i < 4; ++i)
        #pragma unroll
        for (int j = 0; j < 2; ++j)
            acc[i][j] = (f32x16)(0.f);

    const int NT = K >> 6;  // K-tiles of 64 (24 / 32 here; even)

    // ---- prologue: tile0 (4 units) + tile1 Kh0 (2 units), 12 loads ----
    stageA(0, 0, 0); stageB(0, 0, 0);
    stageA(0, 1, 0); stageB(0, 1, 0);
    stageA(1, 0, 1); stageB(1, 0, 1);

    for (int t = 0; t < NT; t += 2) {
        GROUP(0, 1, t);
        GROUP(1, 0, t + 1);
    }

    // Epilogue. C/D: col=lane&31, row=(reg&3)+8*(reg>>2)+4*half (m74/m101)
    if (!FUSE) {
        float bv[2];
        #pragma unroll
        for (int jt = 0; jt < 2; ++jt)
            bv[jt] = bias[col0 + wn * 64 + jt * 32 + l31];
        #pragma unroll
        for (int it = 0; it < 4; ++it) {
            #pragma unroll
            for (int reg = 0; reg < 16; ++reg) {
                const long row = row0 + wm * 128 + it * 32 + (reg & 3) +
                                 8 * (reg >> 2) + 4 * half;
                #pragma unroll
                for (int jt = 0; jt < 2; ++jt) {
                    const long col = col0 + wn * 64 + jt * 32 + l31;
                    float v = fmaxf(acc[it][jt][reg] + bv[jt], 0.f);
                    C[row * N + col] = f2bs(v);
                }
            }
        }
    } else {
        float w3v[2], bv[2];
        #pragma unroll
        for (int jt = 0; jt < 2; ++jt) {
            const long col = col0 + wn * 64 + jt * 32 + l31;
            w3v[jt] = W3[col];
            bv[jt] = bias[col];
        }
        #pragma unroll
        for (int it = 0; it < 4; ++it) {
            #pragma unroll
            for (int reg = 0; reg < 16; ++reg) {
                float s = 0.f;
                #pragma unroll
                for (int jt = 0; jt < 2; ++jt)
                    s += fmaxf(acc[it][jt][reg] + bv[jt], 0.f) * w3v[jt];
                s += __shfl_xor(s, 1, 64);
                s += __shfl_xor(s, 2, 64);
                s += __shfl_xor(s, 4, 64);
                s += __shfl_xor(s, 8, 64);
                s += __shfl_xor(s, 16, 64);
                if (l31 == 0) {
                    const long row = row0 + wm * 128 + it * 32 + (reg & 3) +
                                     8 * (reg >> 2) + 4 * half;
                    atomicAdd(&outp[row], s);
                }
            }
        }
    }
}

// ---------------------------------------------------------------------------
// Launch
// ---------------------------------------------------------------------------
extern "C" void kernel_launch(void* const* d_in, const int* in_sizes, int n_in,
                              void* d_out, int out_size, void* d_ws,
                              size_t ws_size, hipStream_t stream) {
    const float* h  = (const float*)d_in[0];
    const float* W1 = (const float*)d_in[1];
    const float* b1 = (const float*)d_in[2];
    const float* W2 = (const float*)d_in[3];
    const float* b2 = (const float*)d_in[4];
    const float* W3 = (const float*)d_in[5];
    const float* b3 = (const float*)d_in[6];
    float* out = (float*)d_out;

    const int B = 128, T = 254, D = 768, H = 1024;
    const int M = B * T;        // 32512 = 127 * 256
    const int K1 = 2 * D;       // 1536
    const int N1 = 2 * H;       // 2048
    const int K2 = N1;          // 2048
    const int N2 = H;           // 1024
    const int nC = (T + TCHUNK - 1) / TCHUNK;  // 8

    char* ws = (char*)d_ws;
    size_t off = 0;
    auto alloc = [&](size_t bytes) {
        char* p = ws + off;
        off += (bytes + 255) & ~(size_t)255;
        return p;
    };
    unsigned short* X   = (unsigned short*)alloc((size_t)M * K1 * 2);  // 99.9 MB
    unsigned short* H1  = (unsigned short*)alloc((size_t)M * N1 * 2);  // 133.2 MB
    unsigned short* W1T = (unsigned short*)alloc((size_t)N1 * K1 * 2); // 6.3 MB
    unsigned short* W2T = (unsigned short*)alloc((size_t)N2 * K2 * 2); // 4.2 MB
    float* partial      = (float*)alloc((size_t)B * nC * D * 4);       // 3.1 MB

    dim3 tb(32, 8);
    transpose_cast<<<dim3(N1 / 32, K1 / 32), tb, 0, stream>>>(W1, W1T, K1, N1);
    transpose_cast<<<dim3(N2 / 32, K2 / 32), tb, 0, stream>>>(W2, W2T, K2, N2);

    feats_partial<<<dim3(B, nC, D / 256), 256, 0, stream>>>(
        h, partial, X, B, T, D, nC);
    feats_write<<<dim3(B, nC, D / 256), 256, 0, stream>>>(
        partial, X, B, T, D, nC);

    init_out<<<dim3((M + 255) / 256), 256, 0, stream>>>(out, b3, M);

    // 256x256 tiles, 512 threads, 8-phase schedule
    gemm_bt_bias_relu<false><<<dim3((M / 256) * (N1 / 256)), 512, 0, stream>>>(
        X, W1T, b1, H1, nullptr, nullptr, M, N1, K1);
    gemm_bt_bias_relu<true><<<dim3((M / 256) * (N2 / 256)), 512, 0, stream>>>(
        H1, W2T, b2, nullptr, W3, out, M, N2, K2);
}

// Round 2
// 570.792 us; speedup vs baseline: 1.0489x; 1.0074x over previous
//
#include <hip/hip_runtime.h>
#include <hip/hip_bf16.h>

// ---------------------------------------------------------------------------
// Types / helpers
// ---------------------------------------------------------------------------
typedef __bf16 bf16x8 __attribute__((ext_vector_type(8)));
typedef float f32x16 __attribute__((ext_vector_type(16)));

// fp32 -> bf16 bits, round-to-nearest-even (inputs are finite; no NaN path)
__device__ __forceinline__ unsigned short f2bs(float f) {
    unsigned u = __builtin_bit_cast(unsigned, f);
    u = (u + 0x7fffu + ((u >> 16) & 1u)) >> 16;
    return (unsigned short)u;
}
__device__ __forceinline__ float bs2f(unsigned short s) {
    unsigned u = ((unsigned)s) << 16;
    return __builtin_bit_cast(float, u);
}

#define GLDS16(gp, lp)                                                        \
    __builtin_amdgcn_global_load_lds(                                         \
        (const __attribute__((address_space(1))) void*)(gp),                  \
        (__attribute__((address_space(3))) void*)(lp), 16, 0, 0)

#define TCHUNK 32

// ---------------------------------------------------------------------------
// Kernel 1a: per-chunk sums + write the h-half of X in bf16.
// ---------------------------------------------------------------------------
__global__ __launch_bounds__(256) void feats_partial(
    const float* __restrict__ h, float* __restrict__ partial,
    unsigned short* __restrict__ X, int B, int T, int D, int nC) {
    const int d = blockIdx.z * 256 + threadIdx.x;
    const int b = blockIdx.x, c = blockIdx.y;
    const int t0 = c * TCHUNK;
    const int t1 = min(t0 + TCHUNK, T);
    const float* hp = h + ((long)b * T + t0) * D + d;
    unsigned short* xp = X + ((long)b * T + t0) * (2 * D) + D + d;
    float s = 0.f;
    for (int t = t0; t < t1; ++t) {
        float v = *hp;
        *xp = f2bs(v);
        s += v;
        hp += D;
        xp += 2 * D;
    }
    partial[((long)b * nC + c) * D + d] = s;
}

// ---------------------------------------------------------------------------
// Kernel 1b: write the prefix-mean half (reads bf16 h-half back).
// ---------------------------------------------------------------------------
__global__ __launch_bounds__(256) void feats_write(
    const float* __restrict__ partial, unsigned short* __restrict__ X,
    int B, int T, int D, int nC) {
    const int d = blockIdx.z * 256 + threadIdx.x;
    const int b = blockIdx.x, c = blockIdx.y;
    const int t0 = c * TCHUNK;
    const int t1 = min(t0 + TCHUNK, T);
    float sum = 0.f;
    for (int cc = 0; cc < c; ++cc)
        sum += partial[((long)b * nC + cc) * D + d];
    unsigned short* xp = X + ((long)b * T + t0) * (2 * D) + d;
    for (int t = t0; t < t1; ++t) {
        float pm = (t == 0) ? 0.f : sum / (float)t;
        xp[0] = f2bs(pm);
        sum += bs2f(xp[D]);
        xp += 2 * D;
    }
}

// ---------------------------------------------------------------------------
// Kernel 2: transpose + cast. W: [K][N] fp32 -> WT: [N][K] bf16 bits.
// ---------------------------------------------------------------------------
__global__ __launch_bounds__(256) void transpose_cast(
    const float* __restrict__ W, unsigned short* __restrict__ WT,
    int K, int N) {
    __shared__ float tile[32][33];
    const int n0 = blockIdx.x * 32, k0 = blockIdx.y * 32;
    const int tx = threadIdx.x, ty = threadIdx.y;
    #pragma unroll
    for (int i = ty; i < 32; i += 8)
        tile[i][tx] = W[(long)(k0 + i) * N + n0 + tx];
    __syncthreads();
    #pragma unroll
    for (int i = ty; i < 32; i += 8)
        WT[(long)(n0 + i) * K + k0 + tx] = f2bs(tile[tx][i]);
}

// ---------------------------------------------------------------------------
// Kernel 2b: out[m] = b3 (init for the fused-head atomics)
// ---------------------------------------------------------------------------
__global__ __launch_bounds__(256) void init_out(
    float* __restrict__ out, const float* __restrict__ b3, int M) {
    int m = blockIdx.x * 256 + threadIdx.x;
    if (m < M) out[m] = b3[0];
}

// ---------------------------------------------------------------------------
// Kernel 3: GEMM  C[M,N] = relu(A[M,K] * BT[N,K]^T + bias)
//
// R11: 256x256 tile, BK=64, 512 threads (8 waves, 2M x 4N), double-buffered
// with counted vmcnt. CHANGE vs R10 (which measured MfmaUtil 40%):
//   - 3 barriers per K-tile instead of 8. R10's fit: phase = 128cy MFMA +
//     192cy ds_read fully SERIALIZED = 320cy -> 128/320 = 40.0% exactly.
//     Hazard analysis: only 3 sync points are required per K-tile:
//       B1: after the per-wave vmcnt gate (all waves' tile-t loads landed)
//       B2: after ks1 MFMA (last Kh0 reader, before Kh0(t+2) stage issue)
//       B3: after ks3 MFMA (last Kh1 reader, before next group's Kh1 stage)
//     Between barriers, reads of slice k+1 overlap MFMAs of slice k
//     (compiler auto-lgkmcnt) and waves desync -> setprio has roles (T5).
//   - Row-supertile tile order (8 rows x nCol per supertile) under m204
//     XCD chunking: concurrent blocks share 100MB A-panels, not 6MB B.
//     R10's column-major order doubled FETCH (208->402MB).
// Stage schedule per group t (buf c = t&1, o = 1-c), 6-phase issue->consume
// lag, vmcnt(6) = 3 units x 2 loads in flight across barriers (vmcnt(0)
// only for the final K-tile):
//   stretch1: A-Kh1(t+1)->o | stretch2: B-Kh1(t+1)->o
//   stretch3: A-Kh0(t+2)->c, B-Kh0(t+2)->c
// REGISTER MODEL: acc 4x2 f32x16 = 128 acc + ~110 arch -> 2 waves/EU.
// Watch VGPR_Count: if arch > ~128 the freer schedule is over-hoisting.
// LESSONS kept: no min-waves launch_bounds (R4); never exceed 128 acc (R8);
// C/D layout col=lane&31, row=(reg&3)+8*(reg>>2)+4*(lane>>5) (m74/m101).
// ---------------------------------------------------------------------------

#define PH_READS(c, ks, AF, BF)                                               \
    _Pragma("unroll")                                                         \
    for (int m_ = 0; m_ < 4; ++m_)                                            \
        AF[m_] = *(const bf16x8*)(&lds[c][0][(ks) >> 1][0] +                  \
                                  (baseA[m_] ^ (16 * ((ks) & 1))));           \
    _Pragma("unroll")                                                         \
    for (int n_ = 0; n_ < 2; ++n_)                                            \
        BF[n_] = *(const bf16x8*)(&lds[c][1][(ks) >> 1][0] +                  \
                                  (baseB[n_] ^ (16 * ((ks) & 1))));

#define PH_MFMA(AF, BF)                                                       \
    __builtin_amdgcn_s_setprio(1);                                            \
    _Pragma("unroll")                                                         \
    for (int m_ = 0; m_ < 4; ++m_)                                            \
        _Pragma("unroll")                                                     \
        for (int n_ = 0; n_ < 2; ++n_)                                        \
            acc[m_][n_] = __builtin_amdgcn_mfma_f32_32x32x16_bf16(            \
                AF[m_], BF[n_], acc[m_][n_], 0, 0, 0);                        \
    __builtin_amdgcn_s_setprio(0);

#define PH(c, ks)                                                             \
    {                                                                         \
        bf16x8 af[4], bfr[2];                                                 \
        PH_READS(c, ks, af, bfr);                                             \
        PH_MFMA(af, bfr);                                                     \
    }

#define BAR()                                                                 \
    __builtin_amdgcn_sched_barrier(0);                                        \
    __builtin_amdgcn_s_barrier();                                             \
    __builtin_amdgcn_sched_barrier(0);

#define GROUP(c, o, t)                                                        \
  {                                                                           \
    /* stretch 1: stage next A-Kh1, gate on tile t, sync */                   \
    if ((t) + 1 < NT) stageA(o, 1, (t) + 1);                                  \
    if ((t) == NT - 1)                                                        \
        asm volatile("s_waitcnt vmcnt(0)" ::: "memory");                      \
    else                                                                      \
        asm volatile("s_waitcnt vmcnt(6)" ::: "memory");                      \
    BAR();                                                                    \
    /* stretch 2: ks0 + ks1 on Kh0; stage next B-Kh1 */                       \
    PH(c, 0);                                                                 \
    if ((t) + 1 < NT) stageB(o, 1, (t) + 1);                                  \
    PH(c, 1);                                                                 \
    BAR();                                                                    \
    /* stretch 3: ks2 + ks3 on Kh1; stage Kh0(t+2) into freed planes */       \
    if ((t) + 2 < NT) stageA(c, 0, (t) + 2);                                  \
    PH(c, 2);                                                                 \
    if ((t) + 2 < NT) stageB(c, 0, (t) + 2);                                  \
    PH(c, 3);                                                                 \
    BAR();                                                                    \
  }

template <bool FUSE>
__global__ __launch_bounds__(512) void gemm_bt_bias_relu(
    const unsigned short* __restrict__ A,   // [M,K] bf16 bits
    const unsigned short* __restrict__ BT,  // [N,K] bf16 bits
    const float* __restrict__ bias,         // [N]
    unsigned short* __restrict__ C,         // [M,N] bf16 bits (unused if FUSE)
    const float* __restrict__ W3,           // [N] head weights (FUSE only)
    float* __restrict__ outp,               // [M] (FUSE only)
    int M, int N, int K) {
    // [dbuf][A=0/B=1][kh][row*32 + slot*8 .. ] : 128 KiB total
    __shared__ __align__(16) unsigned short lds[2][2][2][8192];

    const int tid = threadIdx.x;
    const int lane = tid & 63;
    const int wave = tid >> 6;
    const int wm = wave >> 2;   // 0..1 -> rows wm*128..+127
    const int wn = wave & 3;    // 0..3 -> cols wn*64..+63
    const int l31 = lane & 31;
    const int half = lane >> 5;

    // ---- m204 bijective XCD chunking over a row-supertile order ----
    const int nRow = M >> 8;            // 127
    const int nCol = N >> 8;            // 8 (GEMM1) / 4 (GEMM2)
    const int nwg = nRow * nCol;
    const int q = nwg >> 3, r = nwg & 7;
    const int x = blockIdx.x & 7;
    const int sidx = blockIdx.x >> 3;
    const int L = (x < r ? x * (q + 1) : r * (q + 1) + (x - r) * q) + sidx;
    // supertile = 8 row-blocks x nCol col-blocks
    const int perSup = 8 * nCol;
    const int nFull = nRow >> 3;        // 15
    const int fullL = nFull * perSup;
    int row_blk, col_blk;
    if (L < fullL) {
        const int sup = L / perSup;
        const int w = L - sup * perSup;
        row_blk = sup * 8 + (w & 7);
        col_blk = w >> 3;
    } else {
        const int rem = L - fullL;
        const int rt = nRow - nFull * 8;  // 7
        row_blk = nFull * 8 + rem % rt;
        col_blk = rem / rt;
    }
    const long row0 = (long)row_blk * 256;
    const long col0 = (long)col_blk * 256;

    // ---- staging source (pre-swizzled global col, rule 21) ----
    // thread covers one 16B chunk: row = tid>>2 (+i*128), slot = tid&3,
    // global chunk = slot ^ ((row>>1)&3) = (tid&3) ^ ((tid>>3)&3)
    const int sg = ((tid & 3) ^ ((tid >> 3) & 3)) * 8;
    const unsigned short* Ab = A + (row0 + (tid >> 2)) * K + sg;
    const unsigned short* Bb = BT + (col0 + (tid >> 2)) * K + sg;

    auto stageA = [&](int c, int kh, int kt) {
        GLDS16(Ab + (long)kt * 64 + kh * 32, &lds[c][0][kh][tid * 8]);
        GLDS16(Ab + (long)128 * K + (long)kt * 64 + kh * 32,
               &lds[c][0][kh][(512 + tid) * 8]);
    };
    auto stageB = [&](int c, int kh, int kt) {
        GLDS16(Bb + (long)kt * 64 + kh * 32, &lds[c][1][kh][tid * 8]);
        GLDS16(Bb + (long)128 * K + (long)kt * 64 + kh * 32,
               &lds[c][1][kh][(512 + tid) * 8]);
    };

    // ---- per-lane LDS read offsets (elements within a plane) ----
    // frag (m, ksub): row = wm*128+m*32+l31, k = ksub*16 + half*8
    // plane = ksub>>1, chunk = half ^ 2*(ksub&1), slot = chunk^((row>>1)&3)
    int baseA[4], baseB[2];
    #pragma unroll
    for (int m = 0; m < 4; ++m) {
        int ra = wm * 128 + m * 32 + l31;
        baseA[m] = ra * 32 + ((half ^ ((ra >> 1) & 3)) * 8);
    }
    #pragma unroll
    for (int n = 0; n < 2; ++n) {
        int rb = wn * 64 + n * 32 + l31;
        baseB[n] = rb * 32 + ((half ^ ((rb >> 1) & 3)) * 8);
    }

    f32x16 acc[4][2];
    #pragma unroll
    for (int i = 0; i < 4; ++i)
        #pragma unroll
        for (int j = 0; j < 2; ++j)
            acc[i][j] = (f32x16)(0.f);

    const int NT = K >> 6;  // K-tiles of 64 (24 / 32 here; even)

    // ---- prologue: tile0 (4 units) + tile1 Kh0 (2 units), 12 loads ----
    stageA(0, 0, 0); stageB(0, 0, 0);
    stageA(0, 1, 0); stageB(0, 1, 0);
    stageA(1, 0, 1); stageB(1, 0, 1);

    for (int t = 0; t < NT; t += 2) {
        GROUP(0, 1, t);
        GROUP(1, 0, t + 1);
    }

    // Epilogue. C/D: col=lane&31, row=(reg&3)+8*(reg>>2)+4*half (m74/m101)
    if (!FUSE) {
        float bv[2];
        #pragma unroll
        for (int jt = 0; jt < 2; ++jt)
            bv[jt] = bias[col0 + wn * 64 + jt * 32 + l31];
        #pragma unroll
        for (int it = 0; it < 4; ++it) {
            #pragma unroll
            for (int reg = 0; reg < 16; ++reg) {
                const long row = row0 + wm * 128 + it * 32 + (reg & 3) +
                                 8 * (reg >> 2) + 4 * half;
                #pragma unroll
                for (int jt = 0; jt < 2; ++jt) {
                    const long col = col0 + wn * 64 + jt * 32 + l31;
                    float v = fmaxf(acc[it][jt][reg] + bv[jt], 0.f);
                    C[row * N + col] = f2bs(v);
                }
            }
        }
    } else {
        float w3v[2], bv[2];
        #pragma unroll
        for (int jt = 0; jt < 2; ++jt) {
            const long col = col0 + wn * 64 + jt * 32 + l31;
            w3v[jt] = W3[col];
            bv[jt] = bias[col];
        }
        #pragma unroll
        for (int it = 0; it < 4; ++it) {
            #pragma unroll
            for (int reg = 0; reg < 16; ++reg) {
                float s = 0.f;
                #pragma unroll
                for (int jt = 0; jt < 2; ++jt)
                    s += fmaxf(acc[it][jt][reg] + bv[jt], 0.f) * w3v[jt];
                s += __shfl_xor(s, 1, 64);
                s += __shfl_xor(s, 2, 64);
                s += __shfl_xor(s, 4, 64);
                s += __shfl_xor(s, 8, 64);
                s += __shfl_xor(s, 16, 64);
                if (l31 == 0) {
                    const long row = row0 + wm * 128 + it * 32 + (reg & 3) +
                                     8 * (reg >> 2) + 4 * half;
                    atomicAdd(&outp[row], s);
                }
            }
        }
    }
}

// ---------------------------------------------------------------------------
// Launch
// ---------------------------------------------------------------------------
extern "C" void kernel_launch(void* const* d_in, const int* in_sizes, int n_in,
                              void* d_out, int out_size, void* d_ws,
                              size_t ws_size, hipStream_t stream) {
    const float* h  = (const float*)d_in[0];
    const float* W1 = (const float*)d_in[1];
    const float* b1 = (const float*)d_in[2];
    const float* W2 = (const float*)d_in[3];
    const float* b2 = (const float*)d_in[4];
    const float* W3 = (const float*)d_in[5];
    const float* b3 = (const float*)d_in[6];
    float* out = (float*)d_out;

    const int B = 128, T = 254, D = 768, H = 1024;
    const int M = B * T;        // 32512 = 127 * 256
    const int K1 = 2 * D;       // 1536
    const int N1 = 2 * H;       // 2048
    const int K2 = N1;          // 2048
    const int N2 = H;           // 1024
    const int nC = (T + TCHUNK - 1) / TCHUNK;  // 8

    char* ws = (char*)d_ws;
    size_t off = 0;
    auto alloc = [&](size_t bytes) {
        char* p = ws + off;
        off += (bytes + 255) & ~(size_t)255;
        return p;
    };
    unsigned short* X   = (unsigned short*)alloc((size_t)M * K1 * 2);  // 99.9 MB
    unsigned short* H1  = (unsigned short*)alloc((size_t)M * N1 * 2);  // 133.2 MB
    unsigned short* W1T = (unsigned short*)alloc((size_t)N1 * K1 * 2); // 6.3 MB
    unsigned short* W2T = (unsigned short*)alloc((size_t)N2 * K2 * 2); // 4.2 MB
    float* partial      = (float*)alloc((size_t)B * nC * D * 4);       // 3.1 MB

    dim3 tb(32, 8);
    transpose_cast<<<dim3(N1 / 32, K1 / 32), tb, 0, stream>>>(W1, W1T, K1, N1);
    transpose_cast<<<dim3(N2 / 32, K2 / 32), tb, 0, stream>>>(W2, W2T, K2, N2);

    feats_partial<<<dim3(B, nC, D / 256), 256, 0, stream>>>(
        h, partial, X, B, T, D, nC);
    feats_write<<<dim3(B, nC, D / 256), 256, 0, stream>>>(
        partial, X, B, T, D, nC);

    init_out<<<dim3((M + 255) / 256), 256, 0, stream>>>(out, b3, M);

    // 256x256 tiles, 512 threads, 3-barrier K-tile schedule
    gemm_bt_bias_relu<false><<<dim3((M / 256) * (N1 / 256)), 512, 0, stream>>>(
        X, W1T, b1, H1, nullptr, nullptr, M, N1, K1);
    gemm_bt_bias_relu<true><<<dim3((M / 256) * (N2 / 256)), 512, 0, stream>>>(
        H1, W2T, b2, nullptr, W3, out, M, N2, K2);
}

// Round 3
// 560.573 us; speedup vs baseline: 1.0680x; 1.0182x over previous
//
#include <hip/hip_runtime.h>
#include <hip/hip_bf16.h>

// ---------------------------------------------------------------------------
// Types / helpers
// ---------------------------------------------------------------------------
typedef __bf16 bf16x8 __attribute__((ext_vector_type(8)));
typedef float f32x16 __attribute__((ext_vector_type(16)));

// fp32 -> bf16 bits, round-to-nearest-even (inputs are finite; no NaN path)
__device__ __forceinline__ unsigned short f2bs(float f) {
    unsigned u = __builtin_bit_cast(unsigned, f);
    u = (u + 0x7fffu + ((u >> 16) & 1u)) >> 16;
    return (unsigned short)u;
}
__device__ __forceinline__ float bs2f(unsigned short s) {
    unsigned u = ((unsigned)s) << 16;
    return __builtin_bit_cast(float, u);
}

#define GLDS16(gp, lp)                                                        \
    __builtin_amdgcn_global_load_lds(                                         \
        (const __attribute__((address_space(1))) void*)(gp),                  \
        (__attribute__((address_space(3))) void*)(lp), 16, 0, 0)

#define TCHUNK 32

// ---------------------------------------------------------------------------
// Kernel 1a: per-chunk sums + write the h-half of X in bf16.
// ---------------------------------------------------------------------------
__global__ __launch_bounds__(256) void feats_partial(
    const float* __restrict__ h, float* __restrict__ partial,
    unsigned short* __restrict__ X, int B, int T, int D, int nC) {
    const int d = blockIdx.z * 256 + threadIdx.x;
    const int b = blockIdx.x, c = blockIdx.y;
    const int t0 = c * TCHUNK;
    const int t1 = min(t0 + TCHUNK, T);
    const float* hp = h + ((long)b * T + t0) * D + d;
    unsigned short* xp = X + ((long)b * T + t0) * (2 * D) + D + d;
    float s = 0.f;
    for (int t = t0; t < t1; ++t) {
        float v = *hp;
        *xp = f2bs(v);
        s += v;
        hp += D;
        xp += 2 * D;
    }
    partial[((long)b * nC + c) * D + d] = s;
}

// ---------------------------------------------------------------------------
// Kernel 1b: write the prefix-mean half (reads bf16 h-half back).
// ---------------------------------------------------------------------------
__global__ __launch_bounds__(256) void feats_write(
    const float* __restrict__ partial, unsigned short* __restrict__ X,
    int B, int T, int D, int nC) {
    const int d = blockIdx.z * 256 + threadIdx.x;
    const int b = blockIdx.x, c = blockIdx.y;
    const int t0 = c * TCHUNK;
    const int t1 = min(t0 + TCHUNK, T);
    float sum = 0.f;
    for (int cc = 0; cc < c; ++cc)
        sum += partial[((long)b * nC + cc) * D + d];
    unsigned short* xp = X + ((long)b * T + t0) * (2 * D) + d;
    for (int t = t0; t < t1; ++t) {
        float pm = (t == 0) ? 0.f : sum / (float)t;
        xp[0] = f2bs(pm);
        sum += bs2f(xp[D]);
        xp += 2 * D;
    }
}

// ---------------------------------------------------------------------------
// Kernel 2: transpose + cast. W: [K][N] fp32 -> WT: [N][K] bf16 bits.
// ---------------------------------------------------------------------------
__global__ __launch_bounds__(256) void transpose_cast(
    const float* __restrict__ W, unsigned short* __restrict__ WT,
    int K, int N) {
    __shared__ float tile[32][33];
    const int n0 = blockIdx.x * 32, k0 = blockIdx.y * 32;
    const int tx = threadIdx.x, ty = threadIdx.y;
    #pragma unroll
    for (int i = ty; i < 32; i += 8)
        tile[i][tx] = W[(long)(k0 + i) * N + n0 + tx];
    __syncthreads();
    #pragma unroll
    for (int i = ty; i < 32; i += 8)
        WT[(long)(n0 + i) * K + k0 + tx] = f2bs(tile[tx][i]);
}

// ---------------------------------------------------------------------------
// Kernel 2b: out[m] = b3 (init for the fused-head atomics)
// ---------------------------------------------------------------------------
__global__ __launch_bounds__(256) void init_out(
    float* __restrict__ out, const float* __restrict__ b3, int M) {
    int m = blockIdx.x * 256 + threadIdx.x;
    if (m < M) out[m] = b3[0];
}

// ---------------------------------------------------------------------------
// Kernel 3: GEMM  C[M,N] = relu(A[M,K] * BT[N,K]^T + bias)
//
// R12: 256x256 tile, BK=64, 512 threads (8 waves, 2M x 4N).
// MODEL RECALIBRATION (R11 post-mortem): mfma_32x32x16 = 32 cy/SIMD pipe
// (m119 2495 TF -> per-CU 8.07 cy = per-SIMD 32). Per block: MFMA busy =
// 49.2k cy/SIMD; measured wall 116.6k -> 42% = measured MfmaUtil ✓.
// LDS read demand (192KB/K-tile over a 2048cy MFMA-bound tile = 96 B/cy)
// is UNDER the LDS cap -> not BW-bound; the ~2.8k cy/K-tile gap is
// exposed latency at sync points.
// CHANGES vs R11 (3 barriers -> 2, + cross-barrier fragment prefetch):
//   - end-barrier merged into gate-barrier: first stage of group t+1 moved
//     AFTER its gate-BAR. Safety: all waves past gate => all issued PH3
//     MFMAs => all Kh1 reads completed (MFMA issue forces lgkm drain) =>
//     overwrite of buf-o Kh1 safe.
//   - stages now all post-gate: {A1(t+1), B1(t+1), A0(t+2), B0(t+2)} =
//     8 loads/group => gate = vmcnt(4) (newest 4 = tile t+2 Kh0 allowed
//     in flight). Prologue order A0(0),B0(0),A1(0),B1(0),A0(1),B0(1)
//     leaves exactly the right newest-4 at the first gate.
//   - ksub2 fragment reads hoisted ABOVE the mid-barrier by hand (Kh1(t)
//     valid since gate; compiler can't cross the fence, we can). Kills
//     the mid-barrier's cold read-latency window. Only PH0 retains an
//     exposed post-barrier read chain (tile validity needs the barrier).
//   - mid-barrier kept: protects buf-c Kh0(t) reads vs A0(t+2) stage.
// REGISTER MODEL: 128 acc + ~128 arch = 256/wave = 2 waves/SIMD boundary.
// Watch VGPR_Count; if >130 arch, trim the prefetch set.
// LESSONS kept: no min-waves launch_bounds (R4); never exceed 128 acc (R8);
// C/D layout col=lane&31, row=(reg&3)+8*(reg>>2)+4*(lane>>5) (m74/m101);
// row-supertile XCD map (R11, FETCH 402->179MB).
// NOT touched this round (isolation): LDS swizzle / bank conflicts
// (1.87e7 = 4 cy/read). If MfmaUtil plateaus ~55%, next lever is
// fragment-major packed layouts.
// ---------------------------------------------------------------------------

#define PH_READS(c, ks, AF, BF)                                               \
    _Pragma("unroll")                                                         \
    for (int m_ = 0; m_ < 4; ++m_)                                            \
        AF[m_] = *(const bf16x8*)(&lds[c][0][(ks) >> 1][0] +                  \
                                  (baseA[m_] ^ (16 * ((ks) & 1))));           \
    _Pragma("unroll")                                                         \
    for (int n_ = 0; n_ < 2; ++n_)                                            \
        BF[n_] = *(const bf16x8*)(&lds[c][1][(ks) >> 1][0] +                  \
                                  (baseB[n_] ^ (16 * ((ks) & 1))));

#define PH_MFMA(AF, BF)                                                       \
    __builtin_amdgcn_s_setprio(1);                                            \
    _Pragma("unroll")                                                         \
    for (int m_ = 0; m_ < 4; ++m_)                                            \
        _Pragma("unroll")                                                     \
        for (int n_ = 0; n_ < 2; ++n_)                                        \
            acc[m_][n_] = __builtin_amdgcn_mfma_f32_32x32x16_bf16(            \
                AF[m_], BF[n_], acc[m_][n_], 0, 0, 0);                        \
    __builtin_amdgcn_s_setprio(0);

#define PH(c, ks)                                                             \
    {                                                                         \
        bf16x8 af[4], bfr[2];                                                 \
        PH_READS(c, ks, af, bfr);                                             \
        PH_MFMA(af, bfr);                                                     \
    }

#define BAR()                                                                 \
    __builtin_amdgcn_sched_barrier(0);                                        \
    __builtin_amdgcn_s_barrier();                                             \
    __builtin_amdgcn_sched_barrier(0);

#define GROUP(c, o, t)                                                        \
  {                                                                           \
    /* gate on tile t (all older stages drained; newest 4 = Kh0(t+2)) */      \
    if ((t) == NT - 1)                                                        \
        asm volatile("s_waitcnt vmcnt(0)" ::: "memory");                      \
    else                                                                      \
        asm volatile("s_waitcnt vmcnt(4)" ::: "memory");                      \
    BAR();                                                                    \
    /* Kh0 half: ksub0+1; stage next-tile Kh1 into buf o */                   \
    if ((t) + 1 < NT) stageA(o, 1, (t) + 1);                                  \
    PH(c, 0);                                                                 \
    if ((t) + 1 < NT) stageB(o, 1, (t) + 1);                                  \
    PH(c, 1);                                                                 \
    /* prefetch ksub2 frags (Kh1(t), valid since gate) across the fence */    \
    bf16x8 a2_[4], b2_[2];                                                    \
    PH_READS(c, 2, a2_, b2_);                                                 \
    BAR(); /* all Kh0(t) reads done (forced by M0/M1 issue) */                \
    if ((t) + 2 < NT) stageA(c, 0, (t) + 2);                                  \
    PH_MFMA(a2_, b2_);                                                        \
    if ((t) + 2 < NT) stageB(c, 0, (t) + 2);                                  \
    PH(c, 3);                                                                 \
  }

template <bool FUSE>
__global__ __launch_bounds__(512) void gemm_bt_bias_relu(
    const unsigned short* __restrict__ A,   // [M,K] bf16 bits
    const unsigned short* __restrict__ BT,  // [N,K] bf16 bits
    const float* __restrict__ bias,         // [N]
    unsigned short* __restrict__ C,         // [M,N] bf16 bits (unused if FUSE)
    const float* __restrict__ W3,           // [N] head weights (FUSE only)
    float* __restrict__ outp,               // [M] (FUSE only)
    int M, int N, int K) {
    // [dbuf][A=0/B=1][kh][row*32 + slot*8 .. ] : 128 KiB total
    __shared__ __align__(16) unsigned short lds[2][2][2][8192];

    const int tid = threadIdx.x;
    const int lane = tid & 63;
    const int wave = tid >> 6;
    const int wm = wave >> 2;   // 0..1 -> rows wm*128..+127
    const int wn = wave & 3;    // 0..3 -> cols wn*64..+63
    const int l31 = lane & 31;
    const int half = lane >> 5;

    // ---- m204 bijective XCD chunking over a row-supertile order ----
    const int nRow = M >> 8;            // 127
    const int nCol = N >> 8;            // 8 (GEMM1) / 4 (GEMM2)
    const int nwg = nRow * nCol;
    const int q = nwg >> 3, r = nwg & 7;
    const int x = blockIdx.x & 7;
    const int sidx = blockIdx.x >> 3;
    const int L = (x < r ? x * (q + 1) : r * (q + 1) + (x - r) * q) + sidx;
    // supertile = 8 row-blocks x nCol col-blocks
    const int perSup = 8 * nCol;
    const int nFull = nRow >> 3;        // 15
    const int fullL = nFull * perSup;
    int row_blk, col_blk;
    if (L < fullL) {
        const int sup = L / perSup;
        const int w = L - sup * perSup;
        row_blk = sup * 8 + (w & 7);
        col_blk = w >> 3;
    } else {
        const int rem = L - fullL;
        const int rt = nRow - nFull * 8;  // 7
        row_blk = nFull * 8 + rem % rt;
        col_blk = rem / rt;
    }
    const long row0 = (long)row_blk * 256;
    const long col0 = (long)col_blk * 256;

    // ---- staging source (pre-swizzled global col, rule 21) ----
    // thread covers one 16B chunk: row = tid>>2 (+i*128), slot = tid&3,
    // global chunk = slot ^ ((row>>1)&3) = (tid&3) ^ ((tid>>3)&3)
    const int sg = ((tid & 3) ^ ((tid >> 3) & 3)) * 8;
    const unsigned short* Ab = A + (row0 + (tid >> 2)) * K + sg;
    const unsigned short* Bb = BT + (col0 + (tid >> 2)) * K + sg;

    auto stageA = [&](int c, int kh, int kt) {
        GLDS16(Ab + (long)kt * 64 + kh * 32, &lds[c][0][kh][tid * 8]);
        GLDS16(Ab + (long)128 * K + (long)kt * 64 + kh * 32,
               &lds[c][0][kh][(512 + tid) * 8]);
    };
    auto stageB = [&](int c, int kh, int kt) {
        GLDS16(Bb + (long)kt * 64 + kh * 32, &lds[c][1][kh][tid * 8]);
        GLDS16(Bb + (long)128 * K + (long)kt * 64 + kh * 32,
               &lds[c][1][kh][(512 + tid) * 8]);
    };

    // ---- per-lane LDS read offsets (elements within a plane) ----
    // frag (m, ksub): row = wm*128+m*32+l31, k = ksub*16 + half*8
    // plane = ksub>>1, chunk = half ^ 2*(ksub&1), slot = chunk^((row>>1)&3)
    int baseA[4], baseB[2];
    #pragma unroll
    for (int m = 0; m < 4; ++m) {
        int ra = wm * 128 + m * 32 + l31;
        baseA[m] = ra * 32 + ((half ^ ((ra >> 1) & 3)) * 8);
    }
    #pragma unroll
    for (int n = 0; n < 2; ++n) {
        int rb = wn * 64 + n * 32 + l31;
        baseB[n] = rb * 32 + ((half ^ ((rb >> 1) & 3)) * 8);
    }

    f32x16 acc[4][2];
    #pragma unroll
    for (int i = 0; i < 4; ++i)
        #pragma unroll
        for (int j = 0; j < 2; ++j)
            acc[i][j] = (f32x16)(0.f);

    const int NT = K >> 6;  // K-tiles of 64 (24 / 32 here; even)

    // ---- prologue: order matters for the first vmcnt(4) gate ----
    // A0(0),B0(0),A1(0),B1(0) then A0(1),B0(1): newest-4 = tile1 Kh0.
    stageA(0, 0, 0); stageB(0, 0, 0);
    stageA(0, 1, 0); stageB(0, 1, 0);
    stageA(1, 0, 1); stageB(1, 0, 1);

    for (int t = 0; t < NT; t += 2) {
        GROUP(0, 1, t);
        GROUP(1, 0, t + 1);
    }

    // Epilogue. C/D: col=lane&31, row=(reg&3)+8*(reg>>2)+4*half (m74/m101)
    if (!FUSE) {
        float bv[2];
        #pragma unroll
        for (int jt = 0; jt < 2; ++jt)
            bv[jt] = bias[col0 + wn * 64 + jt * 32 + l31];
        #pragma unroll
        for (int it = 0; it < 4; ++it) {
            #pragma unroll
            for (int reg = 0; reg < 16; ++reg) {
                const long row = row0 + wm * 128 + it * 32 + (reg & 3) +
                                 8 * (reg >> 2) + 4 * half;
                #pragma unroll
                for (int jt = 0; jt < 2; ++jt) {
                    const long col = col0 + wn * 64 + jt * 32 + l31;
                    float v = fmaxf(acc[it][jt][reg] + bv[jt], 0.f);
                    C[row * N + col] = f2bs(v);
                }
            }
        }
    } else {
        float w3v[2], bv[2];
        #pragma unroll
        for (int jt = 0; jt < 2; ++jt) {
            const long col = col0 + wn * 64 + jt * 32 + l31;
            w3v[jt] = W3[col];
            bv[jt] = bias[col];
        }
        #pragma unroll
        for (int it = 0; it < 4; ++it) {
            #pragma unroll
            for (int reg = 0; reg < 16; ++reg) {
                float s = 0.f;
                #pragma unroll
                for (int jt = 0; jt < 2; ++jt)
                    s += fmaxf(acc[it][jt][reg] + bv[jt], 0.f) * w3v[jt];
                s += __shfl_xor(s, 1, 64);
                s += __shfl_xor(s, 2, 64);
                s += __shfl_xor(s, 4, 64);
                s += __shfl_xor(s, 8, 64);
                s += __shfl_xor(s, 16, 64);
                if (l31 == 0) {
                    const long row = row0 + wm * 128 + it * 32 + (reg & 3) +
                                     8 * (reg >> 2) + 4 * half;
                    atomicAdd(&outp[row], s);
                }
            }
        }
    }
}

// ---------------------------------------------------------------------------
// Launch
// ---------------------------------------------------------------------------
extern "C" void kernel_launch(void* const* d_in, const int* in_sizes, int n_in,
                              void* d_out, int out_size, void* d_ws,
                              size_t ws_size, hipStream_t stream) {
    const float* h  = (const float*)d_in[0];
    const float* W1 = (const float*)d_in[1];
    const float* b1 = (const float*)d_in[2];
    const float* W2 = (const float*)d_in[3];
    const float* b2 = (const float*)d_in[4];
    const float* W3 = (const float*)d_in[5];
    const float* b3 = (const float*)d_in[6];
    float* out = (float*)d_out;

    const int B = 128, T = 254, D = 768, H = 1024;
    const int M = B * T;        // 32512 = 127 * 256
    const int K1 = 2 * D;       // 1536
    const int N1 = 2 * H;       // 2048
    const int K2 = N1;          // 2048
    const int N2 = H;           // 1024
    const int nC = (T + TCHUNK - 1) / TCHUNK;  // 8

    char* ws = (char*)d_ws;
    size_t off = 0;
    auto alloc = [&](size_t bytes) {
        char* p = ws + off;
        off += (bytes + 255) & ~(size_t)255;
        return p;
    };
    unsigned short* X   = (unsigned short*)alloc((size_t)M * K1 * 2);  // 99.9 MB
    unsigned short* H1  = (unsigned short*)alloc((size_t)M * N1 * 2);  // 133.2 MB
    unsigned short* W1T = (unsigned short*)alloc((size_t)N1 * K1 * 2); // 6.3 MB
    unsigned short* W2T = (unsigned short*)alloc((size_t)N2 * K2 * 2); // 4.2 MB
    float* partial      = (float*)alloc((size_t)B * nC * D * 4);       // 3.1 MB

    dim3 tb(32, 8);
    transpose_cast<<<dim3(N1 / 32, K1 / 32), tb, 0, stream>>>(W1, W1T, K1, N1);
    transpose_cast<<<dim3(N2 / 32, K2 / 32), tb, 0, stream>>>(W2, W2T, K2, N2);

    feats_partial<<<dim3(B, nC, D / 256), 256, 0, stream>>>(
        h, partial, X, B, T, D, nC);
    feats_write<<<dim3(B, nC, D / 256), 256, 0, stream>>>(
        partial, X, B, T, D, nC);

    init_out<<<dim3((M + 255) / 256), 256, 0, stream>>>(out, b3, M);

    // 256x256 tiles, 512 threads, 2-barrier K-tile schedule
    gemm_bt_bias_relu<false><<<dim3((M / 256) * (N1 / 256)), 512, 0, stream>>>(
        X, W1T, b1, H1, nullptr, nullptr, M, N1, K1);
    gemm_bt_bias_relu<true><<<dim3((M / 256) * (N2 / 256)), 512, 0, stream>>>(
        H1, W2T, b2, nullptr, W3, out, M, N2, K2);
}

// Round 4
// 559.100 us; speedup vs baseline: 1.0708x; 1.0026x over previous
//
#include <hip/hip_runtime.h>
#include <hip/hip_bf16.h>

// ---------------------------------------------------------------------------
// Types / helpers
// ---------------------------------------------------------------------------
typedef __bf16 bf16x8 __attribute__((ext_vector_type(8)));
typedef float f32x16 __attribute__((ext_vector_type(16)));

// fp32 -> bf16 bits, round-to-nearest-even (inputs are finite; no NaN path)
__device__ __forceinline__ unsigned short f2bs(float f) {
    unsigned u = __builtin_bit_cast(unsigned, f);
    u = (u + 0x7fffu + ((u >> 16) & 1u)) >> 16;
    return (unsigned short)u;
}
__device__ __forceinline__ float bs2f(unsigned short s) {
    unsigned u = ((unsigned)s) << 16;
    return __builtin_bit_cast(float, u);
}

#define GLDS16(gp, lp)                                                        \
    __builtin_amdgcn_global_load_lds(                                         \
        (const __attribute__((address_space(1))) void*)(gp),                  \
        (__attribute__((address_space(3))) void*)(lp), 16, 0, 0)

#define TCHUNK 32

// ---------------------------------------------------------------------------
// Kernel 1a: per-chunk sums + write the h-half of X in bf16.
// ---------------------------------------------------------------------------
__global__ __launch_bounds__(256) void feats_partial(
    const float* __restrict__ h, float* __restrict__ partial,
    unsigned short* __restrict__ X, int B, int T, int D, int nC) {
    const int d = blockIdx.z * 256 + threadIdx.x;
    const int b = blockIdx.x, c = blockIdx.y;
    const int t0 = c * TCHUNK;
    const int t1 = min(t0 + TCHUNK, T);
    const float* hp = h + ((long)b * T + t0) * D + d;
    unsigned short* xp = X + ((long)b * T + t0) * (2 * D) + D + d;
    float s = 0.f;
    for (int t = t0; t < t1; ++t) {
        float v = *hp;
        *xp = f2bs(v);
        s += v;
        hp += D;
        xp += 2 * D;
    }
    partial[((long)b * nC + c) * D + d] = s;
}

// ---------------------------------------------------------------------------
// Kernel 1b: write the prefix-mean half (reads bf16 h-half back).
// ---------------------------------------------------------------------------
__global__ __launch_bounds__(256) void feats_write(
    const float* __restrict__ partial, unsigned short* __restrict__ X,
    int B, int T, int D, int nC) {
    const int d = blockIdx.z * 256 + threadIdx.x;
    const int b = blockIdx.x, c = blockIdx.y;
    const int t0 = c * TCHUNK;
    const int t1 = min(t0 + TCHUNK, T);
    float sum = 0.f;
    for (int cc = 0; cc < c; ++cc)
        sum += partial[((long)b * nC + cc) * D + d];
    unsigned short* xp = X + ((long)b * T + t0) * (2 * D) + d;
    for (int t = t0; t < t1; ++t) {
        float pm = (t == 0) ? 0.f : sum / (float)t;
        xp[0] = f2bs(pm);
        sum += bs2f(xp[D]);
        xp += 2 * D;
    }
}

// ---------------------------------------------------------------------------
// Kernel 2: transpose + cast. W: [K][N] fp32 -> WT: [N][K] bf16 bits.
// ---------------------------------------------------------------------------
__global__ __launch_bounds__(256) void transpose_cast(
    const float* __restrict__ W, unsigned short* __restrict__ WT,
    int K, int N) {
    __shared__ float tile[32][33];
    const int n0 = blockIdx.x * 32, k0 = blockIdx.y * 32;
    const int tx = threadIdx.x, ty = threadIdx.y;
    #pragma unroll
    for (int i = ty; i < 32; i += 8)
        tile[i][tx] = W[(long)(k0 + i) * N + n0 + tx];
    __syncthreads();
    #pragma unroll
    for (int i = ty; i < 32; i += 8)
        WT[(long)(n0 + i) * K + k0 + tx] = f2bs(tile[tx][i]);
}

// ---------------------------------------------------------------------------
// Kernel 2b: out[m] = b3 (init for the fused-head atomics)
// ---------------------------------------------------------------------------
__global__ __launch_bounds__(256) void init_out(
    float* __restrict__ out, const float* __restrict__ b3, int M) {
    int m = blockIdx.x * 256 + threadIdx.x;
    if (m < M) out[m] = b3[0];
}

// ---------------------------------------------------------------------------
// Kernel 3: GEMM  C[M,N] = relu(A[M,K] * BT[N,K]^T + bias)
//
// R13 = R11 schedule (3 barriers/K-tile; best measured 212us/43.5%)
//       + stronger LDS swizzle targeting the constant 1.87e7 bank conflicts.
//
// SCHEDULE LESSON (R12): merging end-barrier into gate (2-barrier) and
// moving all stages post-gate REGRESSED (227us, 40.8%) — post-barrier
// VMEM issue burst collides with the PH0 cold ds_read chain. Keep R11's
// distribution: A-Kh1 staged BEFORE the gate, rest spread mid-group.
//
// SWIZZLE THEORY (R12 post-mortem): conflicts = 4.0 cy per ds_read_b128,
// invariant across schedules => structural. Old swizzle slot=ch^((r>>1)&3)
// is conflict-free only for CONSECUTIVE-8 lane grouping; for stride-8 lane
// sets {l, l+8, ...} (one lane per 8-row stripe) it is CONSTANT =>
// all 8 lanes on one bank quad = 8-way ~ +4cy/read (m136). New swizzle:
//   swz(r) = ((r>>1)&3) ^ ((r>>3)&3)
// consecutive-8: 8 distinct quads (perfect); stride-8 / stride-4 sets:
// 4 quads x 2 = 2-way (free, m136). Applied BOTH sides (rule 21):
// global source chunk and LDS read base use the same swz.
// ASYMMETRIC READ: if SQ_LDS_BANK_CONFLICT does not drop ~10x, conflicts
// are a b128 accounting artifact -> revert swizzle, pivot to non-GEMM time.
//
// MODEL (R11 calibration): mfma_32x32x16 = 32 cy/SIMD pipe; per block MFMA
// busy = 49.2k cy; 4 rounds/CU; MfmaUtil 43.5% == 2.8k cy/K-tile exposed
// latency+sync (LDS BW is NOT the wall: 96 B/cy demand < cap).
// REGISTER MODEL: 128 acc + ~104 arch -> 2 waves/SIMD.
// LESSONS kept: no min-waves launch_bounds (R4); never exceed 128 acc (R8);
// C/D layout col=lane&31, row=(reg&3)+8*(reg>>2)+4*(lane>>5) (m74/m101);
// row-supertile XCD map (R11, FETCH 402->179MB).
// ---------------------------------------------------------------------------

#define PH_READS(c, ks, AF, BF)                                               \
    _Pragma("unroll")                                                         \
    for (int m_ = 0; m_ < 4; ++m_)                                            \
        AF[m_] = *(const bf16x8*)(&lds[c][0][(ks) >> 1][0] +                  \
                                  (baseA[m_] ^ (16 * ((ks) & 1))));           \
    _Pragma("unroll")                                                         \
    for (int n_ = 0; n_ < 2; ++n_)                                            \
        BF[n_] = *(const bf16x8*)(&lds[c][1][(ks) >> 1][0] +                  \
                                  (baseB[n_] ^ (16 * ((ks) & 1))));

#define PH_MFMA(AF, BF)                                                       \
    __builtin_amdgcn_s_setprio(1);                                            \
    _Pragma("unroll")                                                         \
    for (int m_ = 0; m_ < 4; ++m_)                                            \
        _Pragma("unroll")                                                     \
        for (int n_ = 0; n_ < 2; ++n_)                                        \
            acc[m_][n_] = __builtin_amdgcn_mfma_f32_32x32x16_bf16(            \
                AF[m_], BF[n_], acc[m_][n_], 0, 0, 0);                        \
    __builtin_amdgcn_s_setprio(0);

#define PH(c, ks)                                                             \
    {                                                                         \
        bf16x8 af[4], bfr[2];                                                 \
        PH_READS(c, ks, af, bfr);                                             \
        PH_MFMA(af, bfr);                                                     \
    }

#define BAR()                                                                 \
    __builtin_amdgcn_sched_barrier(0);                                        \
    __builtin_amdgcn_s_barrier();                                             \
    __builtin_amdgcn_sched_barrier(0);

#define GROUP(c, o, t)                                                        \
  {                                                                           \
    /* stretch 1: stage next A-Kh1, gate on tile t, sync */                   \
    if ((t) + 1 < NT) stageA(o, 1, (t) + 1);                                  \
    if ((t) == NT - 1)                                                        \
        asm volatile("s_waitcnt vmcnt(0)" ::: "memory");                      \
    else                                                                      \
        asm volatile("s_waitcnt vmcnt(6)" ::: "memory");                      \
    BAR();                                                                    \
    /* stretch 2: ks0 + ks1 on Kh0; stage next B-Kh1 */                       \
    PH(c, 0);                                                                 \
    if ((t) + 1 < NT) stageB(o, 1, (t) + 1);                                  \
    PH(c, 1);                                                                 \
    BAR();                                                                    \
    /* stretch 3: ks2 + ks3 on Kh1; stage Kh0(t+2) into freed planes */       \
    if ((t) + 2 < NT) stageA(c, 0, (t) + 2);                                  \
    PH(c, 2);                                                                 \
    if ((t) + 2 < NT) stageB(c, 0, (t) + 2);                                  \
    PH(c, 3);                                                                 \
    BAR();                                                                    \
  }

template <bool FUSE>
__global__ __launch_bounds__(512) void gemm_bt_bias_relu(
    const unsigned short* __restrict__ A,   // [M,K] bf16 bits
    const unsigned short* __restrict__ BT,  // [N,K] bf16 bits
    const float* __restrict__ bias,         // [N]
    unsigned short* __restrict__ C,         // [M,N] bf16 bits (unused if FUSE)
    const float* __restrict__ W3,           // [N] head weights (FUSE only)
    float* __restrict__ outp,               // [M] (FUSE only)
    int M, int N, int K) {
    // [dbuf][A=0/B=1][kh][row*32 + slot*8 .. ] : 128 KiB total
    __shared__ __align__(16) unsigned short lds[2][2][2][8192];

    const int tid = threadIdx.x;
    const int lane = tid & 63;
    const int wave = tid >> 6;
    const int wm = wave >> 2;   // 0..1 -> rows wm*128..+127
    const int wn = wave & 3;    // 0..3 -> cols wn*64..+63
    const int l31 = lane & 31;
    const int half = lane >> 5;

    // ---- m204 bijective XCD chunking over a row-supertile order ----
    const int nRow = M >> 8;            // 127
    const int nCol = N >> 8;            // 8 (GEMM1) / 4 (GEMM2)
    const int nwg = nRow * nCol;
    const int q = nwg >> 3, r = nwg & 7;
    const int x = blockIdx.x & 7;
    const int sidx = blockIdx.x >> 3;
    const int L = (x < r ? x * (q + 1) : r * (q + 1) + (x - r) * q) + sidx;
    // supertile = 8 row-blocks x nCol col-blocks
    const int perSup = 8 * nCol;
    const int nFull = nRow >> 3;        // 15
    const int fullL = nFull * perSup;
    int row_blk, col_blk;
    if (L < fullL) {
        const int sup = L / perSup;
        const int w = L - sup * perSup;
        row_blk = sup * 8 + (w & 7);
        col_blk = w >> 3;
    } else {
        const int rem = L - fullL;
        const int rt = nRow - nFull * 8;  // 7
        row_blk = nFull * 8 + rem % rt;
        col_blk = rem / rt;
    }
    const long row0 = (long)row_blk * 256;
    const long col0 = (long)col_blk * 256;

    // ---- staging source (pre-swizzled global col, rule 21) ----
    // thread covers 16B chunk: row = tid>>2 (+128 for 2nd load), slot=tid&3.
    // global chunk = slot ^ swz(row), swz(r) = ((r>>1)&3) ^ ((r>>3)&3)
    //   row = tid>>2  =>  swz = ((tid>>3)&3) ^ ((tid>>5)&3)
    // (+128 row offset leaves both terms unchanged: bits below 7 untouched)
    const int sg = ((tid & 3) ^ ((tid >> 3) & 3) ^ ((tid >> 5) & 3)) * 8;
    const unsigned short* Ab = A + (row0 + (tid >> 2)) * K + sg;
    const unsigned short* Bb = BT + (col0 + (tid >> 2)) * K + sg;

    auto stageA = [&](int c, int kh, int kt) {
        GLDS16(Ab + (long)kt * 64 + kh * 32, &lds[c][0][kh][tid * 8]);
        GLDS16(Ab + (long)128 * K + (long)kt * 64 + kh * 32,
               &lds[c][0][kh][(512 + tid) * 8]);
    };
    auto stageB = [&](int c, int kh, int kt) {
        GLDS16(Bb + (long)kt * 64 + kh * 32, &lds[c][1][kh][tid * 8]);
        GLDS16(Bb + (long)128 * K + (long)kt * 64 + kh * 32,
               &lds[c][1][kh][(512 + tid) * 8]);
    };

    // ---- per-lane LDS read offsets (elements within a plane) ----
    // frag (m, ksub): row = wm*128+m*32+l31, k = ksub*16 + half*8
    // plane = ksub>>1, chunk = half ^ 2*(ksub&1),
    // slot = chunk ^ ((row>>1)&3) ^ ((row>>3)&3)
    // (ksub XOR 16*(ks&1) composes: flips slot bit 1, base bits 3..4 clear)
    int baseA[4], baseB[2];
    #pragma unroll
    for (int m = 0; m < 4; ++m) {
        int ra = wm * 128 + m * 32 + l31;
        baseA[m] = ra * 32 + ((half ^ ((ra >> 1) & 3) ^ ((ra >> 3) & 3)) * 8);
    }
    #pragma unroll
    for (int n = 0; n < 2; ++n) {
        int rb = wn * 64 + n * 32 + l31;
        baseB[n] = rb * 32 + ((half ^ ((rb >> 1) & 3) ^ ((rb >> 3) & 3)) * 8);
    }

    f32x16 acc[4][2];
    #pragma unroll
    for (int i = 0; i < 4; ++i)
        #pragma unroll
        for (int j = 0; j < 2; ++j)
            acc[i][j] = (f32x16)(0.f);

    const int NT = K >> 6;  // K-tiles of 64 (24 / 32 here; even)

    // ---- prologue: tile0 (4 units) + tile1 Kh0 (2 units), 12 loads ----
    stageA(0, 0, 0); stageB(0, 0, 0);
    stageA(0, 1, 0); stageB(0, 1, 0);
    stageA(1, 0, 1); stageB(1, 0, 1);

    for (int t = 0; t < NT; t += 2) {
        GROUP(0, 1, t);
        GROUP(1, 0, t + 1);
    }

    // Epilogue. C/D: col=lane&31, row=(reg&3)+8*(reg>>2)+4*half (m74/m101)
    if (!FUSE) {
        float bv[2];
        #pragma unroll
        for (int jt = 0; jt < 2; ++jt)
            bv[jt] = bias[col0 + wn * 64 + jt * 32 + l31];
        #pragma unroll
        for (int it = 0; it < 4; ++it) {
            #pragma unroll
            for (int reg = 0; reg < 16; ++reg) {
                const long row = row0 + wm * 128 + it * 32 + (reg & 3) +
                                 8 * (reg >> 2) + 4 * half;
                #pragma unroll
                for (int jt = 0; jt < 2; ++jt) {
                    const long col = col0 + wn * 64 + jt * 32 + l31;
                    float v = fmaxf(acc[it][jt][reg] + bv[jt], 0.f);
                    C[row * N + col] = f2bs(v);
                }
            }
        }
    } else {
        float w3v[2], bv[2];
        #pragma unroll
        for (int jt = 0; jt < 2; ++jt) {
            const long col = col0 + wn * 64 + jt * 32 + l31;
            w3v[jt] = W3[col];
            bv[jt] = bias[col];
        }
        #pragma unroll
        for (int it = 0; it < 4; ++it) {
            #pragma unroll
            for (int reg = 0; reg < 16; ++reg) {
                float s = 0.f;
                #pragma unroll
                for (int jt = 0; jt < 2; ++jt)
                    s += fmaxf(acc[it][jt][reg] + bv[jt], 0.f) * w3v[jt];
                s += __shfl_xor(s, 1, 64);
                s += __shfl_xor(s, 2, 64);
                s += __shfl_xor(s, 4, 64);
                s += __shfl_xor(s, 8, 64);
                s += __shfl_xor(s, 16, 64);
                if (l31 == 0) {
                    const long row = row0 + wm * 128 + it * 32 + (reg & 3) +
                                     8 * (reg >> 2) + 4 * half;
                    atomicAdd(&outp[row], s);
                }
            }
        }
    }
}

// ---------------------------------------------------------------------------
// Launch
// ---------------------------------------------------------------------------
extern "C" void kernel_launch(void* const* d_in, const int* in_sizes, int n_in,
                              void* d_out, int out_size, void* d_ws,
                              size_t ws_size, hipStream_t stream) {
    const float* h  = (const float*)d_in[0];
    const float* W1 = (const float*)d_in[1];
    const float* b1 = (const float*)d_in[2];
    const float* W2 = (const float*)d_in[3];
    const float* b2 = (const float*)d_in[4];
    const float* W3 = (const float*)d_in[5];
    const float* b3 = (const float*)d_in[6];
    float* out = (float*)d_out;

    const int B = 128, T = 254, D = 768, H = 1024;
    const int M = B * T;        // 32512 = 127 * 256
    const int K1 = 2 * D;       // 1536
    const int N1 = 2 * H;       // 2048
    const int K2 = N1;          // 2048
    const int N2 = H;           // 1024
    const int nC = (T + TCHUNK - 1) / TCHUNK;  // 8

    char* ws = (char*)d_ws;
    size_t off = 0;
    auto alloc = [&](size_t bytes) {
        char* p = ws + off;
        off += (bytes + 255) & ~(size_t)255;
        return p;
    };
    unsigned short* X   = (unsigned short*)alloc((size_t)M * K1 * 2);  // 99.9 MB
    unsigned short* H1  = (unsigned short*)alloc((size_t)M * N1 * 2);  // 133.2 MB
    unsigned short* W1T = (unsigned short*)alloc((size_t)N1 * K1 * 2); // 6.3 MB
    unsigned short* W2T = (unsigned short*)alloc((size_t)N2 * K2 * 2); // 4.2 MB
    float* partial      = (float*)alloc((size_t)B * nC * D * 4);       // 3.1 MB

    dim3 tb(32, 8);
    transpose_cast<<<dim3(N1 / 32, K1 / 32), tb, 0, stream>>>(W1, W1T, K1, N1);
    transpose_cast<<<dim3(N2 / 32, K2 / 32), tb, 0, stream>>>(W2, W2T, K2, N2);

    feats_partial<<<dim3(B, nC, D / 256), 256, 0, stream>>>(
        h, partial, X, B, T, D, nC);
    feats_write<<<dim3(B, nC, D / 256), 256, 0, stream>>>(
        partial, X, B, T, D, nC);

    init_out<<<dim3((M + 255) / 256), 256, 0, stream>>>(out, b3, M);

    // 256x256 tiles, 512 threads, 3-barrier K-tile schedule
    gemm_bt_bias_relu<false><<<dim3((M / 256) * (N1 / 256)), 512, 0, stream>>>(
        X, W1T, b1, H1, nullptr, nullptr, M, N1, K1);
    gemm_bt_bias_relu<true><<<dim3((M / 256) * (N2 / 256)), 512, 0, stream>>>(
        H1, W2T, b2, nullptr, W3, out, M, N2, K2);
}